// Round 1
// baseline (4829.692 us; speedup 1.0000x reference)
//
#include <hip/hip_runtime.h>
#include <cstdint>
#include <cstddef>

#define V_ 32000
#define E_ 512
#define H_ 1024
#define S_ 512
#define T_ 512
#define G4 4096  // 4*H

typedef unsigned long long u64;

// hardware-approx transcendentals (v_exp_f32 / v_rcp_f32, ~1 ulp)
__device__ __forceinline__ float fexp2(float x) { return __builtin_amdgcn_exp2f(x); }
__device__ __forceinline__ float sigm(float x) {
  return __builtin_amdgcn_rcpf(1.0f + fexp2(x * -1.442695041f));
}
__device__ __forceinline__ float ftanh(float x) {
  return 2.0f * __builtin_amdgcn_rcpf(1.0f + fexp2(x * -2.885390082f)) - 1.0f;
}

// ---------------------------------------------------------------------------
// Xi[t, r] = emb[tok[t]] . Wih[r, :] + b1[r] + b2[r]
// tile 64t x 64r, BK=32, 256 threads, 4x4 micro-tile. K-major LDS (stride 68).
// (unchanged from the 2647 us version)
// ---------------------------------------------------------------------------
__global__ __launch_bounds__(256) void xi_gemm(
    const float* __restrict__ emb, const int* __restrict__ tok,
    const float* __restrict__ Wih, const float* __restrict__ b1,
    const float* __restrict__ b2, float* __restrict__ Xi) {
  __shared__ float As[32][68];
  __shared__ float Bs[32][68];
  __shared__ int ids[64];
  const int tid = threadIdx.x;
  const int tx = tid & 15, ty = tid >> 4;
  const int t0 = blockIdx.y * 64, r0 = blockIdx.x * 64;
  if (tid < 64) ids[tid] = tok[t0 + tid];
  __syncthreads();
  const int lrow = tid >> 2;        // 0..63
  const int lk   = (tid & 3) * 8;   // 0,8,16,24
  const long arow = (long)ids[lrow] * E_;
  const long brow = (long)(r0 + lrow) * E_;
  float acc[4][4] = {};
  for (int k0 = 0; k0 < E_; k0 += 32) {
    float4 a0 = *(const float4*)(emb + arow + k0 + lk);
    float4 a1 = *(const float4*)(emb + arow + k0 + lk + 4);
    float4 w0 = *(const float4*)(Wih + brow + k0 + lk);
    float4 w1 = *(const float4*)(Wih + brow + k0 + lk + 4);
    __syncthreads();  // previous compute done before overwriting LDS
    As[lk + 0][lrow] = a0.x; As[lk + 1][lrow] = a0.y; As[lk + 2][lrow] = a0.z; As[lk + 3][lrow] = a0.w;
    As[lk + 4][lrow] = a1.x; As[lk + 5][lrow] = a1.y; As[lk + 6][lrow] = a1.z; As[lk + 7][lrow] = a1.w;
    Bs[lk + 0][lrow] = w0.x; Bs[lk + 1][lrow] = w0.y; Bs[lk + 2][lrow] = w0.z; Bs[lk + 3][lrow] = w0.w;
    Bs[lk + 4][lrow] = w1.x; Bs[lk + 5][lrow] = w1.y; Bs[lk + 6][lrow] = w1.z; Bs[lk + 7][lrow] = w1.w;
    __syncthreads();
#pragma unroll
    for (int kk = 0; kk < 32; ++kk) {
      float4 av = *(const float4*)&As[kk][ty * 4];
      float4 bv = *(const float4*)&Bs[kk][tx * 4];
      float a_[4] = {av.x, av.y, av.z, av.w};
      float b_[4] = {bv.x, bv.y, bv.z, bv.w};
#pragma unroll
      for (int i = 0; i < 4; ++i)
#pragma unroll
        for (int j = 0; j < 4; ++j) acc[i][j] += a_[i] * b_[j];
    }
  }
#pragma unroll
  for (int i = 0; i < 4; ++i) {
    const int t = t0 + ty * 4 + i;
#pragma unroll
    for (int j = 0; j < 4; ++j) {
      const int r = r0 + tx * 4 + j;
      Xi[(size_t)t * G4 + r] = acc[i][j] + b1[r] + b2[r];
    }
  }
}

// ---------------------------------------------------------------------------
// Fused persistent kernel: 256 WGs x 1024 threads (exactly 1 block/CU, so all
// blocks are co-resident regardless of dispatch order -> no deadlock mode).
//   blocks 0..63   : LSTM recurrence (proven v4 structure, 4-acc dot added).
//     - hs stores are relaxed AGENT atomic stores (write-through to L3) and a
//       per-WG progress word is RELEASE-stored after them (wave-level
//       vmcnt(0) drains all 16 publish lanes' stores first).
//   blocks 64..255 : logits workers. Steal (tb, vb) tiles in tb-ascending
//     order via atomic counter; gate each tile on
//     min_wg(prog) >= 640 + tb*128 (decoder rows t0..t0+127 published),
//     wave-0-only relaxed polling + one ACQUIRE load (invalidates this CU's
//     L1/L2 path before the plain float4 hs reads). 128x128 tile, BK=32,
//     4x4 micro, K-major PHYS-padded LDS; row max/sum via intra-32-lane
//     shuffles (no LDS reduction arrays).
// ---------------------------------------------------------------------------
#define PHYS(j) ((j) + (((j) >> 5) << 2))  // +4-word shift per 32-col block

__global__ __launch_bounds__(1024, 4) void lstm_logits(
    const float* __restrict__ Xi_enc, const float* __restrict__ Xi_dec,
    const float* __restrict__ Whh_enc, const float* __restrict__ Whh_dec,
    u64* __restrict__ hpair,        // [2][1024] (tag<<32)|f32bits, memset 0
    float* __restrict__ hs,         // [512][1024] decoder hidden states
    const float* __restrict__ Wout, const float* __restrict__ bout,
    const int* __restrict__ tgt,
    unsigned* __restrict__ prog,    // [64] per-WG step progress, memset 0
    unsigned* __restrict__ ctr,     // tile work-steal counter, memset 0
    float* __restrict__ pmax, float* __restrict__ psum,
    float* __restrict__ tgtlog) {
  __shared__ float h_lds[2][16 * 68 + 4];  // lstm: chunk-major, stride 68
  __shared__ float gh[16];                 // lstm: per-wave h handoff
  __shared__ float As[32][140];            // worker: K-major A tile
  __shared__ float Bs[32][140];            // worker: K-major B tile
  __shared__ int tile_s;                   // worker: stolen tile index
  const int tid = threadIdx.x;
  const int wv = tid >> 6;   // wave 0..15
  const int ln = tid & 63;   // lane

  if (blockIdx.x < 64) {
    // ------------------------- LSTM recurrence role -------------------------
    const int wg = blockIdx.x;
    const int g  = ln >> 4;         // gate 0..3 (i,f,g,o)
    const int c  = ln & 15;         // h chunk [c*64, c*64+64)
    const int unit = wg * 16 + wv;
    const int grow = g * H_ + unit;
    const int c64 = c * 64;

    float4 w[16];
    {
      const float* wp = Whh_enc + (size_t)grow * H_ + c64;
#pragma unroll
      for (int q = 0; q < 16; ++q) w[q] = *(const float4*)(wp + q * 4);
    }
    const float* Xi = Xi_enc;
    float cstate = 0.f, h_own = 0.f;
    int dead = 0;

    for (int s = 0; s < 1024; ++s) {
      if (s == 512) {  // encoder -> decoder transition
        const float* wp = Whh_dec + (size_t)grow * H_ + c64;
#pragma unroll
        for (int q = 0; q < 16; ++q) w[q] = *(const float4*)(wp + q * 4);
        Xi = Xi_dec;
        cstate = ftanh(h_own);  // dc0 = tanh(enc_h); dh0 = enc_h (in pairs)
      }
      float xi = 0.f;
      if (c == 0) xi = Xi[(size_t)(s & 511) * G4 + grow];

      // poll OWN pair: wave's 64 consecutive 8B loads coalesce; ballot exit
      const u64* pb = hpair + (size_t)(s & 1) * H_;
      const unsigned want = (unsigned)s;
      u64 p;
      {
        int tries = 0;
        for (;;) {
          p = __hip_atomic_load(pb + tid, __ATOMIC_RELAXED, __HIP_MEMORY_SCOPE_AGENT);
          bool ok = ((unsigned)(p >> 32) == want);
          if (__ballot(ok) == ~0ull || dead) break;
          if (++tries > (1 << 20)) { dead = 1; break; }  // hang safety
          __builtin_amdgcn_s_sleep(1);
        }
      }
      float* buf = h_lds[s & 1];
      buf[wv * 68 + ln] = __uint_as_float((unsigned)p);
      __syncthreads();  // barrier A: h staged

      // 4 independent accumulators: dependent-FMA chain 64 -> ~16
      float a0 = 0.f, a1 = 0.f, a2 = 0.f, a3 = 0.f;
      const float* hb = &buf[c * 68];
#pragma unroll
      for (int q = 0; q < 16; ++q) {
        float4 h4 = *(const float4*)(hb + q * 4);
        a0 += w[q].x * h4.x; a1 += w[q].y * h4.y;
        a2 += w[q].z * h4.z; a3 += w[q].w * h4.w;
      }
      float acc = (a0 + a1) + (a2 + a3);
      acc += __shfl_xor(acc, 8, 64);
      acc += __shfl_xor(acc, 4, 64);
      acc += __shfl_xor(acc, 2, 64);
      acc += __shfl_xor(acc, 1, 64);
      float val = acc + xi;  // gate sums live on lanes 0,16,32,48

      float act = (g == 2) ? ftanh(val) : sigm(val);
      float i_ = __shfl(act, 0, 64);
      float f_ = __shfl(act, 16, 64);
      float g_ = __shfl(act, 32, 64);
      float o_ = __shfl(act, 48, 64);
      cstate = f_ * cstate + i_ * g_;
      float h = o_ * ftanh(cstate);
      h_own = h;
      if (ln == 0) gh[wv] = h;
      __syncthreads();  // barrier B: all 16 unit-h values in gh[]

      if (wv == 0 && ln < 16) {  // ONE coalesced 128B publish per WG
        float hv = gh[ln];
        const int k = wg * 16 + ln;
        u64 pair = ((u64)(unsigned)(s + 1) << 32) | (u64)__float_as_uint(hv);
        __hip_atomic_store(hpair + (size_t)((s + 1) & 1) * H_ + k, pair,
                           __ATOMIC_RELAXED, __HIP_MEMORY_SCOPE_AGENT);
        if (s >= 512)  // write-through so in-kernel readers can see it
          __hip_atomic_store(hs + (size_t)(s - 512) * H_ + k, hv,
                             __ATOMIC_RELAXED, __HIP_MEMORY_SCOPE_AGENT);
        if (ln == 0)   // release: vmcnt(0) drains the wave's hs/pair stores
          __hip_atomic_store(prog + wg, (unsigned)(s + 1),
                             __ATOMIC_RELEASE, __HIP_MEMORY_SCOPE_AGENT);
      }
    }
  } else {
    // --------------------------- logits worker role --------------------------
    const int ty = tid >> 5, tx = tid & 31;   // 32x32 thread grid, 4x4 micro
    const int lrow = tid >> 3;                // 0..127 (staging row)
    const int lk   = (tid & 7) * 4;           // 0..28  (staging k quad)
    const int pl   = PHYS(lrow);
    const int aoff = PHYS(ty * 4), boff = PHYS(tx * 4);

    for (;;) {
      if (tid == 0) tile_s = (int)atomicAdd(ctr, 1u);
      __syncthreads();                        // tile_s visible to block
      const int idx = tile_s;
      if (idx >= 1000) break;                 // 4 t-blocks x 250 v-blocks
      const int tb = idx / 250, vb = idx - tb * 250;

      // gate: all 64 lstm WGs past decoder step tb*128+127  (prog >= 640+tb*128)
      if (wv == 0) {
        const unsigned need = 640u + (unsigned)tb * 128u;
        int tries = 0;
        for (;;) {
          unsigned pr = __hip_atomic_load(prog + ln, __ATOMIC_RELAXED,
                                          __HIP_MEMORY_SCOPE_AGENT);
          if (__ballot(pr >= need) == ~0ull) break;
          if (++tries > (1 << 20)) break;     // hang safety
          __builtin_amdgcn_s_sleep(16);       // throttle poll traffic
        }
        (void)__hip_atomic_load(prog + ln, __ATOMIC_ACQUIRE,
                                __HIP_MEMORY_SCOPE_AGENT);  // invalidate path
      }
      __syncthreads();                        // whole block gated

      const int t0 = tb * 128, v0 = vb * 128;
      const float* ap = hs + (size_t)(t0 + lrow) * H_ + lk;
      const float* bp = Wout + (size_t)(v0 + lrow) * H_ + lk;
      float acc[4][4] = {};
      for (int k0 = 0; k0 < H_; k0 += 32) {
        float4 a = *(const float4*)(ap + k0);
        float4 b = *(const float4*)(bp + k0);
        __syncthreads();  // previous compute done before overwriting LDS
        As[lk + 0][pl] = a.x; As[lk + 1][pl] = a.y;
        As[lk + 2][pl] = a.z; As[lk + 3][pl] = a.w;
        Bs[lk + 0][pl] = b.x; Bs[lk + 1][pl] = b.y;
        Bs[lk + 2][pl] = b.z; Bs[lk + 3][pl] = b.w;
        __syncthreads();
#pragma unroll
        for (int kk = 0; kk < 32; ++kk) {
          float4 av = *(const float4*)&As[kk][aoff];
          float4 bv = *(const float4*)&Bs[kk][boff];
          float a_[4] = {av.x, av.y, av.z, av.w};
          float b_[4] = {bv.x, bv.y, bv.z, bv.w};
#pragma unroll
          for (int i = 0; i < 4; ++i)
#pragma unroll
            for (int j = 0; j < 4; ++j) acc[i][j] += a_[i] * b_[j];
        }
      }
      // ---- fused epilogue: bias, row max/sumexp via 32-lane shuffles ----
      float bj[4];
#pragma unroll
      for (int j = 0; j < 4; ++j) bj[j] = bout[v0 + tx * 4 + j];
#pragma unroll
      for (int i = 0; i < 4; ++i) {
        const int t = t0 + ty * 4 + i;
        float m = -3.0e38f;
#pragma unroll
        for (int j = 0; j < 4; ++j) { acc[i][j] += bj[j]; m = fmaxf(m, acc[i][j]); }
#pragma unroll
        for (int d = 16; d > 0; d >>= 1) m = fmaxf(m, __shfl_xor(m, d, 64));
        float sum = 0.f;
#pragma unroll
        for (int j = 0; j < 4; ++j) sum += expf(acc[i][j] - m);
#pragma unroll
        for (int d = 16; d > 0; d >>= 1) sum += __shfl_xor(sum, d, 64);
        if (tx == 0) {
          pmax[(size_t)t * 250 + vb] = m;
          psum[(size_t)t * 250 + vb] = sum;
        }
        const int loc = tgt[t] - v0 - tx * 4;
        if (loc >= 0 && loc < 4) {
#pragma unroll
          for (int j = 0; j < 4; ++j)
            if (j == loc) tgtlog[t] = acc[i][j];  // static idx: no scratch
        }
      }
      // next iteration's steal-sync + gate-sync separate LDS reuse
    }
  }
}

// ---------------------------------------------------------------------------
// combine 250 (max, sumexp) partials per row -> loss[t] = lse - logit[target]
// ---------------------------------------------------------------------------
__global__ __launch_bounds__(256) void reduce_loss(
    const float* __restrict__ pmax, const float* __restrict__ psum,
    const float* __restrict__ tgtlog, float* __restrict__ out) {
  __shared__ float sm[256];
  __shared__ float ss[256];
  const int t = blockIdx.x, tid = threadIdx.x;
  float m = -3.0e38f;
  if (tid < 250) m = pmax[(size_t)t * 250 + tid];
  sm[tid] = m;
  __syncthreads();
  for (int s = 128; s > 0; s >>= 1) {
    if (tid < s) sm[tid] = fmaxf(sm[tid], sm[tid + s]);
    __syncthreads();
  }
  const float M = sm[0];
  float sv = 0.f;
  if (tid < 250) sv = psum[(size_t)t * 250 + tid] * expf(m - M);
  ss[tid] = sv;
  __syncthreads();
  for (int s = 128; s > 0; s >>= 1) {
    if (tid < s) ss[tid] += ss[tid + s];
    __syncthreads();
  }
  if (tid == 0) out[t] = M + logf(ss[0]) - tgtlog[t];
}

// ---------------------------------------------------------------------------
extern "C" void kernel_launch(void* const* d_in, const int* in_sizes, int n_in,
                              void* d_out, int out_size, void* d_ws, size_t ws_size,
                              hipStream_t stream) {
  const int*   source    = (const int*)  d_in[0];
  const int*   target    = (const int*)  d_in[1];
  const float* enc_embed = (const float*)d_in[2];
  const float* enc_Wih   = (const float*)d_in[3];
  const float* enc_Whh   = (const float*)d_in[4];
  const float* enc_bih   = (const float*)d_in[5];
  const float* enc_bhh   = (const float*)d_in[6];
  const float* dec_embed = (const float*)d_in[7];
  const float* dec_Wih   = (const float*)d_in[8];
  const float* dec_Whh   = (const float*)d_in[9];
  const float* dec_bih   = (const float*)d_in[10];
  const float* dec_bhh   = (const float*)d_in[11];
  const float* Wout      = (const float*)d_in[12];
  const float* bout      = (const float*)d_in[13];
  float* out = (float*)d_out;

  char* ws = (char*)d_ws;
  float*    Xi_enc = (float*)   (ws);              // 512*4096*4 = 8 MB
  float*    Xi_dec = (float*)   (ws + 8388608);    // 8 MB
  float*    hs     = (float*)   (ws + 16777216);   // 2 MB
  u64*      hpair  = (u64*)     (ws + 18874368);   // 16 KB
  unsigned* prog   = (unsigned*)(ws + 18890752);   // 256 B
  unsigned* ctr    = (unsigned*)(ws + 18891008);   // 4 B
  float*    pmax   = (float*)   (ws + 18891776);   // 512*250*4 = 500 KB
  float*    psum   = (float*)   (ws + 19403776);   // 500 KB
  float*    tgtlog = (float*)   (ws + 19915776);   // 2 KB

  // zero hpair (h0=0, tag=0) + prog + ctr in one pass
  hipMemsetAsync((void*)hpair, 0, 16644, stream);
  xi_gemm<<<dim3(64, 8), 256, 0, stream>>>(enc_embed, source, enc_Wih, enc_bih, enc_bhh, Xi_enc);
  xi_gemm<<<dim3(64, 8), 256, 0, stream>>>(dec_embed, target, dec_Wih, dec_bih, dec_bhh, Xi_dec);
  lstm_logits<<<256, 1024, 0, stream>>>(Xi_enc, Xi_dec, enc_Whh, dec_Whh, hpair, hs,
                                        Wout, bout, target, prog, ctr, pmax, psum, tgtlog);
  reduce_loss<<<512, 256, 0, stream>>>(pmax, psum, tgtlog, out);
}

// Round 2
// 2575.272 us; speedup vs baseline: 1.8754x; 1.8754x over previous
//
#include <hip/hip_runtime.h>
#include <cstdint>
#include <cstddef>

#define V_ 32000
#define E_ 512
#define H_ 1024
#define S_ 512
#define T_ 512
#define G4 4096  // 4*H

typedef unsigned long long u64;

// hardware-approx transcendentals (v_exp_f32 / v_rcp_f32, ~1 ulp)
__device__ __forceinline__ float fexp2(float x) { return __builtin_amdgcn_exp2f(x); }
__device__ __forceinline__ float sigm(float x) {
  return __builtin_amdgcn_rcpf(1.0f + fexp2(x * -1.442695041f));
}
__device__ __forceinline__ float ftanh(float x) {
  return 2.0f * __builtin_amdgcn_rcpf(1.0f + fexp2(x * -2.885390082f)) - 1.0f;
}

// ---------------------------------------------------------------------------
// Xi[t, r] = emb[tok[t]] . Wih[r, :] + b1[r] + b2[r]
// tile 64t x 64r, BK=32, 256 threads, 4x4 micro-tile. K-major LDS (stride 68).
// ---------------------------------------------------------------------------
__global__ __launch_bounds__(256) void xi_gemm(
    const float* __restrict__ emb, const int* __restrict__ tok,
    const float* __restrict__ Wih, const float* __restrict__ b1,
    const float* __restrict__ b2, float* __restrict__ Xi) {
  __shared__ float As[32][68];
  __shared__ float Bs[32][68];
  __shared__ int ids[64];
  const int tid = threadIdx.x;
  const int tx = tid & 15, ty = tid >> 4;
  const int t0 = blockIdx.y * 64, r0 = blockIdx.x * 64;
  if (tid < 64) ids[tid] = tok[t0 + tid];
  __syncthreads();
  const int lrow = tid >> 2;        // 0..63
  const int lk   = (tid & 3) * 8;   // 0,8,16,24
  const long arow = (long)ids[lrow] * E_;
  const long brow = (long)(r0 + lrow) * E_;
  float acc[4][4] = {};
  for (int k0 = 0; k0 < E_; k0 += 32) {
    float4 a0 = *(const float4*)(emb + arow + k0 + lk);
    float4 a1 = *(const float4*)(emb + arow + k0 + lk + 4);
    float4 w0 = *(const float4*)(Wih + brow + k0 + lk);
    float4 w1 = *(const float4*)(Wih + brow + k0 + lk + 4);
    __syncthreads();  // previous compute done before overwriting LDS
    As[lk + 0][lrow] = a0.x; As[lk + 1][lrow] = a0.y; As[lk + 2][lrow] = a0.z; As[lk + 3][lrow] = a0.w;
    As[lk + 4][lrow] = a1.x; As[lk + 5][lrow] = a1.y; As[lk + 6][lrow] = a1.z; As[lk + 7][lrow] = a1.w;
    Bs[lk + 0][lrow] = w0.x; Bs[lk + 1][lrow] = w0.y; Bs[lk + 2][lrow] = w0.z; Bs[lk + 3][lrow] = w0.w;
    Bs[lk + 4][lrow] = w1.x; Bs[lk + 5][lrow] = w1.y; Bs[lk + 6][lrow] = w1.z; Bs[lk + 7][lrow] = w1.w;
    __syncthreads();
#pragma unroll
    for (int kk = 0; kk < 32; ++kk) {
      float4 av = *(const float4*)&As[kk][ty * 4];
      float4 bv = *(const float4*)&Bs[kk][tx * 4];
      float a_[4] = {av.x, av.y, av.z, av.w};
      float b_[4] = {bv.x, bv.y, bv.z, bv.w};
#pragma unroll
      for (int i = 0; i < 4; ++i)
#pragma unroll
        for (int j = 0; j < 4; ++j) acc[i][j] += a_[i] * b_[j];
    }
  }
#pragma unroll
  for (int i = 0; i < 4; ++i) {
    const int t = t0 + ty * 4 + i;
#pragma unroll
    for (int j = 0; j < 4; ++j) {
      const int r = r0 + tx * 4 + j;
      Xi[(size_t)t * G4 + r] = acc[i][j] + b1[r] + b2[r];
    }
  }
}

// ---------------------------------------------------------------------------
// Fused persistent kernel v2: 256 WGs x 1024 threads.
//   waves_per_eu(4,4): min=max=4 waves/SIMD -> compiler has no incentive to
//   squeeze VGPRs to 64; w[16] stays register-resident, and any alloc >=65
//   VGPRs makes a 2nd block/CU unplaceable -> LSTM blocks get DEDICATED CUs
//   (v1's 64-VGPR alloc allowed 2 blocks/CU: logits workers stacked on LSTM
//   CUs and weights were reloaded per step -> 2.2x step-latency regression).
//   blocks 0..63   : LSTM recurrence (proven structure).
//     - hs stores: relaxed AGENT write-through (in-kernel visibility).
//     - prog release only at epoch steps s=639/767/895/1023 (the only
//       granularity workers gate on) -> 4 vmcnt(0) fences total, not 1024.
//   blocks 64..255 : logits workers, tile-steal in tb-ascending order,
//     gate on min_wg(prog) >= 640 + tb*128, acquire before hs reads.
// ---------------------------------------------------------------------------
#define PHYS(j) ((j) + (((j) >> 5) << 2))  // +4-word shift per 32-col block

__global__ __attribute__((amdgpu_flat_work_group_size(1024, 1024)))
__attribute__((amdgpu_waves_per_eu(4, 4))) void lstm_logits(
    const float* __restrict__ Xi_enc, const float* __restrict__ Xi_dec,
    const float* __restrict__ Whh_enc, const float* __restrict__ Whh_dec,
    u64* __restrict__ hpair,        // [2][1024] (tag<<32)|f32bits, memset 0
    float* __restrict__ hs,         // [512][1024] decoder hidden states
    const float* __restrict__ Wout, const float* __restrict__ bout,
    const int* __restrict__ tgt,
    unsigned* __restrict__ prog,    // [64] per-WG step progress, memset 0
    unsigned* __restrict__ ctr,     // tile work-steal counter, memset 0
    float* __restrict__ pmax, float* __restrict__ psum,
    float* __restrict__ tgtlog) {
  __shared__ float h_lds[2][16 * 68 + 4];  // lstm: chunk-major, stride 68
  __shared__ float gh[16];                 // lstm: per-wave h handoff
  __shared__ float As[32][140];            // worker: K-major A tile
  __shared__ float Bs[32][140];            // worker: K-major B tile
  __shared__ int tile_s;                   // worker: stolen tile index
  const int tid = threadIdx.x;
  const int wv = tid >> 6;   // wave 0..15
  const int ln = tid & 63;   // lane

  if (blockIdx.x < 64) {
    // ------------------------- LSTM recurrence role -------------------------
    const int wg = blockIdx.x;
    const int g  = ln >> 4;         // gate 0..3 (i,f,g,o)
    const int c  = ln & 15;         // h chunk [c*64, c*64+64)
    const int unit = wg * 16 + wv;
    const int grow = g * H_ + unit;
    const int c64 = c * 64;

    float4 w[16];
    {
      const float* wp = Whh_enc + (size_t)grow * H_ + c64;
#pragma unroll
      for (int q = 0; q < 16; ++q) w[q] = *(const float4*)(wp + q * 4);
    }
    const float* Xi = Xi_enc;
    float cstate = 0.f, h_own = 0.f;
    int dead = 0;

    for (int s = 0; s < 1024; ++s) {
      if (s == 512) {  // encoder -> decoder transition
        const float* wp = Whh_dec + (size_t)grow * H_ + c64;
#pragma unroll
        for (int q = 0; q < 16; ++q) w[q] = *(const float4*)(wp + q * 4);
        Xi = Xi_dec;
        cstate = ftanh(h_own);  // dc0 = tanh(enc_h); dh0 = enc_h (in pairs)
      }
      float xi = 0.f;
      if (c == 0) xi = Xi[(size_t)(s & 511) * G4 + grow];

      // poll OWN pair: wave's 64 consecutive 8B loads coalesce; ballot exit
      const u64* pb = hpair + (size_t)(s & 1) * H_;
      const unsigned want = (unsigned)s;
      u64 p;
      {
        int tries = 0;
        for (;;) {
          p = __hip_atomic_load(pb + tid, __ATOMIC_RELAXED, __HIP_MEMORY_SCOPE_AGENT);
          bool ok = ((unsigned)(p >> 32) == want);
          if (__ballot(ok) == ~0ull || dead) break;
          if (++tries > (1 << 21)) { dead = 1; break; }  // hang safety
          __builtin_amdgcn_s_sleep(1);
        }
      }
      float* buf = h_lds[s & 1];
      buf[wv * 68 + ln] = __uint_as_float((unsigned)p);
      __syncthreads();  // barrier A: h staged

      // 4 independent accumulators: dependent-FMA chain 64 -> 16
      float a0 = 0.f, a1 = 0.f, a2 = 0.f, a3 = 0.f;
      const float* hb = &buf[c * 68];
#pragma unroll
      for (int q = 0; q < 16; ++q) {
        float4 h4 = *(const float4*)(hb + q * 4);
        a0 += w[q].x * h4.x; a1 += w[q].y * h4.y;
        a2 += w[q].z * h4.z; a3 += w[q].w * h4.w;
      }
      float acc = (a0 + a1) + (a2 + a3);
      acc += __shfl_xor(acc, 8, 64);
      acc += __shfl_xor(acc, 4, 64);
      acc += __shfl_xor(acc, 2, 64);
      acc += __shfl_xor(acc, 1, 64);
      float val = acc + xi;  // gate sums live on lanes 0,16,32,48

      float act = (g == 2) ? ftanh(val) : sigm(val);
      float i_ = __shfl(act, 0, 64);
      float f_ = __shfl(act, 16, 64);
      float g_ = __shfl(act, 32, 64);
      float o_ = __shfl(act, 48, 64);
      cstate = f_ * cstate + i_ * g_;
      float h = o_ * ftanh(cstate);
      h_own = h;
      if (ln == 0) gh[wv] = h;
      __syncthreads();  // barrier B: all 16 unit-h values in gh[]

      if (wv == 0 && ln < 16) {  // ONE coalesced 128B publish per WG
        float hv = gh[ln];
        const int k = wg * 16 + ln;
        u64 pair = ((u64)(unsigned)(s + 1) << 32) | (u64)__float_as_uint(hv);
        __hip_atomic_store(hpair + (size_t)((s + 1) & 1) * H_ + k, pair,
                           __ATOMIC_RELAXED, __HIP_MEMORY_SCOPE_AGENT);
        if (s >= 512)  // write-through so in-kernel readers can see it
          __hip_atomic_store(hs + (size_t)(s - 512) * H_ + k, hv,
                             __ATOMIC_RELAXED, __HIP_MEMORY_SCOPE_AGENT);
        // epoch release only (s=639/767/895/1023): drains the wave's hs
        // stores for the epoch, then publishes progress for worker gates.
        if (ln == 0 && s >= 639 && (s & 127) == 127)
          __hip_atomic_store(prog + wg, (unsigned)(s + 1),
                             __ATOMIC_RELEASE, __HIP_MEMORY_SCOPE_AGENT);
      }
    }
  } else {
    // --------------------------- logits worker role --------------------------
    const int ty = tid >> 5, tx = tid & 31;   // 32x32 thread grid, 4x4 micro
    const int lrow = tid >> 3;                // 0..127 (staging row)
    const int lk   = (tid & 7) * 4;           // 0..28  (staging k quad)
    const int pl   = PHYS(lrow);
    const int aoff = PHYS(ty * 4), boff = PHYS(tx * 4);

    for (;;) {
      if (tid == 0) tile_s = (int)atomicAdd(ctr, 1u);
      __syncthreads();                        // tile_s visible to block
      const int idx = tile_s;
      if (idx >= 1000) break;                 // 4 t-blocks x 250 v-blocks
      const int tb = idx / 250, vb = idx - tb * 250;

      // gate: all 64 lstm WGs past decoder step tb*128+127 (prog >= 640+tb*128)
      if (wv == 0) {
        const unsigned need = 640u + (unsigned)tb * 128u;
        int tries = 0;
        for (;;) {
          unsigned pr = __hip_atomic_load(prog + ln, __ATOMIC_RELAXED,
                                          __HIP_MEMORY_SCOPE_AGENT);
          if (__ballot(pr >= need) == ~0ull) break;
          if (++tries > (1 << 22)) break;     // hang safety
          __builtin_amdgcn_s_sleep(64);       // throttle poll traffic
        }
        (void)__hip_atomic_load(prog + ln, __ATOMIC_ACQUIRE,
                                __HIP_MEMORY_SCOPE_AGENT);  // invalidate path
      }
      __syncthreads();                        // whole block gated

      const int t0 = tb * 128, v0 = vb * 128;
      const float* ap = hs + (size_t)(t0 + lrow) * H_ + lk;
      const float* bp = Wout + (size_t)(v0 + lrow) * H_ + lk;
      float acc[4][4] = {};
      for (int k0 = 0; k0 < H_; k0 += 32) {
        float4 a = *(const float4*)(ap + k0);
        float4 b = *(const float4*)(bp + k0);
        __syncthreads();  // previous compute done before overwriting LDS
        As[lk + 0][pl] = a.x; As[lk + 1][pl] = a.y;
        As[lk + 2][pl] = a.z; As[lk + 3][pl] = a.w;
        Bs[lk + 0][pl] = b.x; Bs[lk + 1][pl] = b.y;
        Bs[lk + 2][pl] = b.z; Bs[lk + 3][pl] = b.w;
        __syncthreads();
#pragma unroll
        for (int kk = 0; kk < 32; ++kk) {
          float4 av = *(const float4*)&As[kk][aoff];
          float4 bv = *(const float4*)&Bs[kk][boff];
          float a_[4] = {av.x, av.y, av.z, av.w};
          float b_[4] = {bv.x, bv.y, bv.z, bv.w};
#pragma unroll
          for (int i = 0; i < 4; ++i)
#pragma unroll
            for (int j = 0; j < 4; ++j) acc[i][j] += a_[i] * b_[j];
        }
      }
      // ---- fused epilogue: bias, row max/sumexp via 32-lane shuffles ----
      float bj[4];
#pragma unroll
      for (int j = 0; j < 4; ++j) bj[j] = bout[v0 + tx * 4 + j];
#pragma unroll
      for (int i = 0; i < 4; ++i) {
        const int t = t0 + ty * 4 + i;
        float m = -3.0e38f;
#pragma unroll
        for (int j = 0; j < 4; ++j) { acc[i][j] += bj[j]; m = fmaxf(m, acc[i][j]); }
#pragma unroll
        for (int d = 16; d > 0; d >>= 1) m = fmaxf(m, __shfl_xor(m, d, 64));
        float sum = 0.f;
#pragma unroll
        for (int j = 0; j < 4; ++j) sum += expf(acc[i][j] - m);
#pragma unroll
        for (int d = 16; d > 0; d >>= 1) sum += __shfl_xor(sum, d, 64);
        if (tx == 0) {
          pmax[(size_t)t * 250 + vb] = m;
          psum[(size_t)t * 250 + vb] = sum;
        }
        const int loc = tgt[t] - v0 - tx * 4;
        if (loc >= 0 && loc < 4) {
#pragma unroll
          for (int j = 0; j < 4; ++j)
            if (j == loc) tgtlog[t] = acc[i][j];  // static idx: no scratch
        }
      }
      // next iteration's steal-sync + gate-sync separate LDS reuse
    }
  }
}

// ---------------------------------------------------------------------------
// combine 250 (max, sumexp) partials per row -> loss[t] = lse - logit[target]
// ---------------------------------------------------------------------------
__global__ __launch_bounds__(256) void reduce_loss(
    const float* __restrict__ pmax, const float* __restrict__ psum,
    const float* __restrict__ tgtlog, float* __restrict__ out) {
  __shared__ float sm[256];
  __shared__ float ss[256];
  const int t = blockIdx.x, tid = threadIdx.x;
  float m = -3.0e38f;
  if (tid < 250) m = pmax[(size_t)t * 250 + tid];
  sm[tid] = m;
  __syncthreads();
  for (int s = 128; s > 0; s >>= 1) {
    if (tid < s) sm[tid] = fmaxf(sm[tid], sm[tid + s]);
    __syncthreads();
  }
  const float M = sm[0];
  float sv = 0.f;
  if (tid < 250) sv = psum[(size_t)t * 250 + tid] * expf(m - M);
  ss[tid] = sv;
  __syncthreads();
  for (int s = 128; s > 0; s >>= 1) {
    if (tid < s) ss[tid] += ss[tid + s];
    __syncthreads();
  }
  if (tid == 0) out[t] = M + logf(ss[0]) - tgtlog[t];
}

// ---------------------------------------------------------------------------
extern "C" void kernel_launch(void* const* d_in, const int* in_sizes, int n_in,
                              void* d_out, int out_size, void* d_ws, size_t ws_size,
                              hipStream_t stream) {
  const int*   source    = (const int*)  d_in[0];
  const int*   target    = (const int*)  d_in[1];
  const float* enc_embed = (const float*)d_in[2];
  const float* enc_Wih   = (const float*)d_in[3];
  const float* enc_Whh   = (const float*)d_in[4];
  const float* enc_bih   = (const float*)d_in[5];
  const float* enc_bhh   = (const float*)d_in[6];
  const float* dec_embed = (const float*)d_in[7];
  const float* dec_Wih   = (const float*)d_in[8];
  const float* dec_Whh   = (const float*)d_in[9];
  const float* dec_bih   = (const float*)d_in[10];
  const float* dec_bhh   = (const float*)d_in[11];
  const float* Wout      = (const float*)d_in[12];
  const float* bout      = (const float*)d_in[13];
  float* out = (float*)d_out;

  char* ws = (char*)d_ws;
  float*    Xi_enc = (float*)   (ws);              // 512*4096*4 = 8 MB
  float*    Xi_dec = (float*)   (ws + 8388608);    // 8 MB
  float*    hs     = (float*)   (ws + 16777216);   // 2 MB
  u64*      hpair  = (u64*)     (ws + 18874368);   // 16 KB
  unsigned* prog   = (unsigned*)(ws + 18890752);   // 256 B
  unsigned* ctr    = (unsigned*)(ws + 18891008);   // 4 B
  float*    pmax   = (float*)   (ws + 18891776);   // 512*250*4 = 500 KB
  float*    psum   = (float*)   (ws + 19403776);   // 500 KB
  float*    tgtlog = (float*)   (ws + 19915776);   // 2 KB

  // zero hpair (h0=0, tag=0) + prog + ctr in one pass
  hipMemsetAsync((void*)hpair, 0, 16644, stream);
  xi_gemm<<<dim3(64, 8), 256, 0, stream>>>(enc_embed, source, enc_Wih, enc_bih, enc_bhh, Xi_enc);
  xi_gemm<<<dim3(64, 8), 256, 0, stream>>>(dec_embed, target, dec_Wih, dec_bih, dec_bhh, Xi_dec);
  lstm_logits<<<256, 1024, 0, stream>>>(Xi_enc, Xi_dec, enc_Whh, dec_Whh, hpair, hs,
                                        Wout, bout, target, prog, ctr, pmax, psum, tgtlog);
  reduce_loss<<<512, 256, 0, stream>>>(pmax, psum, tgtlog, out);
}